// Round 6
// baseline (7257.954 us; speedup 1.0000x reference)
//
#include <hip/hip_runtime.h>
#include <hip/hip_bf16.h>
#include <math.h>

#define BB 256
#define TT 512
#define INW 128
#define EH 512
#define GH 512

#define NGB 16           // blocks per group (column slices)
#define MGH 8            // batch rows per multiplexed group
#define NB 32            // output cols per block (2 x 16-col tiles)
#define FLS 16           // flag stride in u32 (64 B)

typedef __attribute__((ext_vector_type(8))) short bf16x8;
typedef __attribute__((ext_vector_type(4))) float f32x4;
typedef __attribute__((ext_vector_type(2))) unsigned long long u64x2;

__device__ __forceinline__ float sigm(float x){ return 1.0f/(1.0f+__expf(-x)); }
__device__ __forceinline__ short f2bf(float x){
    __hip_bfloat16 h = __float2bfloat16(x);
    return *reinterpret_cast<short*>(&h);
}

// ---- IC-coherent (agent-scope, relaxed) data path — the PROVEN r3/r4 mechanism --------------
__device__ __forceinline__ unsigned long long ld_coh64(const unsigned long long* p){
    return __hip_atomic_load(p, __ATOMIC_RELAXED, __HIP_MEMORY_SCOPE_AGENT);
}
__device__ __forceinline__ void st_coh32(unsigned* p, unsigned v){
    __hip_atomic_store(p, v, __ATOMIC_RELAXED, __HIP_MEMORY_SCOPE_AGENT);
}
__device__ __forceinline__ void wait_vm0(){ asm volatile("s_waitcnt vmcnt(0)" ::: "memory"); }

// staged 16B chunk: issue early (loads in flight), write to swizzled LDS late
struct Stg { unsigned long long q0, q1; };
__device__ __forceinline__ Stg stage_issue(const short* rowbase, int kb){
    const unsigned long long* gp = (const unsigned long long*)((const char*)rowbase + kb);
    Stg s; s.q0 = ld_coh64(gp); s.q1 = ld_coh64(gp + 1); return s;
}
__device__ __forceinline__ void stage_write(char* sbuf, int row, int kb, Stg s){
    u64x2 v; v[0] = s.q0; v[1] = s.q1;
    *(u64x2*)(sbuf + row*1024 + (kb ^ (row << 4))) = v;
}

// poll 16 peer flags (64 lanes, 4 lanes/flag) until all >= e; trailing block sync
__device__ __forceinline__ void poll16(const unsigned* fl, unsigned e){
    if (threadIdx.x < 64){
        const unsigned* p = fl + (threadIdx.x & (NGB-1)) * FLS;
        long spins = 0;
        for(;;){
            unsigned v = __hip_atomic_load(p, __ATOMIC_RELAXED, __HIP_MEMORY_SCOPE_AGENT);
            if (__all((int)(v >= e))) break;
            if (++spins > (1L << 20)) break;   // escape hatch, never hit legitimately
        }
    }
    __syncthreads();
}

// x-tile write: 4 bf16 (8B) at swizzled offset
__device__ __forceinline__ void xwrite(char* sX, int row, int kf, float4 f){
    short4 v;
    v.x = f2bf(f.x); v.y = f2bf(f.y); v.z = f2bf(f.z); v.w = f2bf(f.w);
    *(short4*)(sX + row*256 + ((kf*2) ^ (row << 4))) = v;
}

// ---------------- encoder per-group compute (one GRU step, 8 valid rows) ----------------------
__device__ __forceinline__ void enc_compute(
    const char* sH, const char* sX, float* sR, float* sZ, float* sHfp,
    const bf16x8* whB, const bf16x8* wxB,
    short* hdst, float* hencf, const int b0, const int j0,
    const int wid, const int l15, const int lk, const int ct, const int col,
    const bool last)
{
    f32x4 acc0 = {0.f,0.f,0.f,0.f}, acc1 = {0.f,0.f,0.f,0.f}, accx = {0.f,0.f,0.f,0.f};
    if (wid < 6){
        const int r8 = l15 & 7;
        const int asw = r8 << 4;
        const char* hb = sH + r8*1024;
        const char* xb = sX + r8*256;
        #pragma unroll
        for (int kt = 0; kt < 8; ++kt){ int kb = kt*64 + lk*16;
            bf16x8 a = *(const bf16x8*)(hb + (kb ^ asw));
            acc0 = __builtin_amdgcn_mfma_f32_16x16x32_bf16(a, whB[kt], acc0, 0, 0, 0); }
        #pragma unroll
        for (int kt = 8; kt < 16; ++kt){ int kb = kt*64 + lk*16;
            bf16x8 a = *(const bf16x8*)(hb + (kb ^ asw));
            acc1 = __builtin_amdgcn_mfma_f32_16x16x32_bf16(a, whB[kt], acc1, 0, 0, 0); }
        #pragma unroll
        for (int kt = 0; kt < 4; ++kt){ int kb = kt*64 + lk*16;
            bf16x8 a = *(const bf16x8*)(xb + (kb ^ asw));
            accx = __builtin_amdgcn_mfma_f32_16x16x32_bf16(a, wxB[kt], accx, 0, 0, 0); }
    }
    f32x4 acch = acc0 + acc1;
    if (wid < 2){
        #pragma unroll
        for (int v = 0; v < 4; ++v){ int row = lk*4 + v;
            if (row < MGH) sR[row*33 + col] = sigm(accx[v] + acch[v]); }
    } else if (wid < 4){
        #pragma unroll
        for (int v = 0; v < 4; ++v){ int row = lk*4 + v;
            if (row < MGH) sZ[row*33 + col] = sigm(accx[v] + acch[v]); }
    }
    __syncthreads();
    if (wid == 4 || wid == 5){
        #pragma unroll
        for (int v = 0; v < 4; ++v){ int row = lk*4 + v;
            if (row < MGH){
                float r  = sR[row*33 + col];
                float z  = sZ[row*33 + col];
                float n  = tanhf(accx[v] + r * acch[v]);
                float hp = sHfp[row*33 + col];
                float hn = (1.f - z)*n + z*hp;
                sHfp[row*33 + col] = hn;
                unsigned mine = (unsigned short)f2bf(hn);
                unsigned oth  = __shfl_xor(mine, 1);
                if (!(l15 & 1))
                    st_coh32((unsigned*)&hdst[(size_t)(b0 + row)*EH + j0 + ct*16 + (l15 & ~1)],
                             (oth << 16) | mine);
                if (last) hencf[(size_t)(b0 + row)*EH + j0 + col] = hn;
            }
        }
    }
}

// ---------------- generator phase 1 (r,u) and phase 2 (c,combine) ------------------------------
__device__ __forceinline__ void gen_ph1(
    const char* sH, float* sU, const float* sHfp, const bf16x8* wB,
    short* rhg, const int j0, const int wid, const int l15, const int lk,
    const int ct, const int col)
{
    if (wid < 4){
        const int r8 = l15 & 7, asw = r8 << 4;
        const char* hb = sH + r8*1024;
        f32x4 a0 = {0.f,0.f,0.f,0.f}, a1 = {0.f,0.f,0.f,0.f};
        #pragma unroll
        for (int kt = 0; kt < 8; ++kt){ int kb = kt*64 + lk*16;
            bf16x8 a = *(const bf16x8*)(hb + (kb ^ asw));
            a0 = __builtin_amdgcn_mfma_f32_16x16x32_bf16(a, wB[kt], a0, 0, 0, 0); }
        #pragma unroll
        for (int kt = 8; kt < 16; ++kt){ int kb = kt*64 + lk*16;
            bf16x8 a = *(const bf16x8*)(hb + (kb ^ asw));
            a1 = __builtin_amdgcn_mfma_f32_16x16x32_bf16(a, wB[kt], a1, 0, 0, 0); }
        f32x4 acc = a0 + a1;
        if (wid < 2){
            #pragma unroll
            for (int v = 0; v < 4; ++v){ int row = lk*4 + v;
                if (row < MGH){
                    float hp = sHfp[row*33 + col];
                    float rv = sigm(acc[v]);
                    unsigned mine = (unsigned short)f2bf(rv * hp);
                    unsigned oth  = __shfl_xor(mine, 1);
                    if (!(l15 & 1))
                        st_coh32((unsigned*)&rhg[(size_t)row*GH + j0 + ct*16 + (l15 & ~1)],
                                 (oth << 16) | mine);
                }}
        } else {
            #pragma unroll
            for (int v = 0; v < 4; ++v){ int row = lk*4 + v;
                if (row < MGH) sU[row*33 + col] = sigm(acc[v] + 1.0f); }
        }
    }
}

__device__ __forceinline__ void gen_ph2(
    const char* sH /*rh*/, const float* sU, float* sHfp, const bf16x8* wB,
    short* hdst, const int b0, const int j0, const int wid, const int l15,
    const int lk, const int ct, const int col, float* hvv)
{
    if (wid == 4 || wid == 5){
        const int r8 = l15 & 7, asw = r8 << 4;
        const char* hb = sH + r8*1024;
        f32x4 a0 = {0.f,0.f,0.f,0.f}, a1 = {0.f,0.f,0.f,0.f};
        #pragma unroll
        for (int kt = 0; kt < 8; ++kt){ int kb = kt*64 + lk*16;
            bf16x8 a = *(const bf16x8*)(hb + (kb ^ asw));
            a0 = __builtin_amdgcn_mfma_f32_16x16x32_bf16(a, wB[kt], a0, 0, 0, 0); }
        #pragma unroll
        for (int kt = 8; kt < 16; ++kt){ int kb = kt*64 + lk*16;
            bf16x8 a = *(const bf16x8*)(hb + (kb ^ asw));
            a1 = __builtin_amdgcn_mfma_f32_16x16x32_bf16(a, wB[kt], a1, 0, 0, 0); }
        f32x4 acc = a0 + a1;
        #pragma unroll
        for (int v = 0; v < 4; ++v){ int row = lk*4 + v;
            if (row < MGH){
                float cv = tanhf(acc[v]);
                float u  = sU[row*33 + col];
                float hp = sHfp[row*33 + col];
                float hn = u*hp + (1.0f - u)*cv;
                sHfp[row*33 + col] = hn;
                hvv[v] = hn;
                unsigned mine = (unsigned short)f2bf(hn);
                unsigned oth  = __shfl_xor(mine, 1);
                if (!(l15 & 1))
                    st_coh32((unsigned*)&hdst[(size_t)(b0 + row)*GH + j0 + ct*16 + (l15 & ~1)],
                             (oth << 16) | mine);
            }
        }
    }
}

// ================= ENCODER: 2-way group time-multiplex ========================================
__global__ __launch_bounds__(512, 1) void enc_kernel(
    const float* __restrict__ src,   // [256][512][128]
    const float* __restrict__ Wi,    // [1536][128] rows r,z,n
    const float* __restrict__ Wh,    // [1536][512]
    short*       __restrict__ hbf,   // [2][256][512] bf16 ping-pong, slot0 zeroed
    float*       __restrict__ hencf, // [256][512] f32 final state
    unsigned*    __restrict__ flags)
{
    __shared__ __align__(16) char sHA[MGH*1024];
    __shared__ __align__(16) char sHB[MGH*1024];
    __shared__ __align__(16) char sXA[MGH*256];
    __shared__ __align__(16) char sXB[MGH*256];
    __shared__ float sR[MGH*33], sZ[MGH*33];
    __shared__ float sHfpA[MGH*33], sHfpB[MGH*33];

    const int bid = blockIdx.x;
    const int pr = bid >> 4, ng = bid & 15;          // pair index / column slice
    const int tid = threadIdx.x;
    const int wid = tid >> 6, lane = tid & 63;
    const int l15 = lane & 15, lk = lane >> 4;
    const int j0 = ng * NB;
    const int b0A = pr * 16, b0B = pr * 16 + 8;
    unsigned* flA = flags + (size_t)((pr << 1) | 0) * (NGB * FLS);
    unsigned* flB = flags + (size_t)((pr << 1) | 1) * (NGB * FLS);

    const int gate = wid >> 1, ct = wid & 1;
    const int col = ct*16 + l15;

    // persistent weight fragments (shared by groups A and B)
    bf16x8 whB[16], wxB[4];
    if (wid < 6){
        const float* wrh = Wh + (size_t)(gate*EH + j0 + col) * EH;
        const float* wrx = Wi + (size_t)(gate*EH + j0 + col) * INW;
        #pragma unroll
        for (int kt = 0; kt < 16; ++kt){
            int ke = kt*32 + lk*8;
            float4 f0 = *(const float4*)(wrh + ke);
            float4 f1 = *(const float4*)(wrh + ke + 4);
            bf16x8 v;
            v[0]=f2bf(f0.x); v[1]=f2bf(f0.y); v[2]=f2bf(f0.z); v[3]=f2bf(f0.w);
            v[4]=f2bf(f1.x); v[5]=f2bf(f1.y); v[6]=f2bf(f1.z); v[7]=f2bf(f1.w);
            whB[kt] = v;
        }
        #pragma unroll
        for (int kt = 0; kt < 4; ++kt){
            int ke = kt*32 + lk*8;
            float4 f0 = *(const float4*)(wrx + ke);
            float4 f1 = *(const float4*)(wrx + ke + 4);
            bf16x8 v;
            v[0]=f2bf(f0.x); v[1]=f2bf(f0.y); v[2]=f2bf(f0.z); v[3]=f2bf(f0.w);
            v[4]=f2bf(f1.x); v[5]=f2bf(f1.y); v[6]=f2bf(f1.z); v[7]=f2bf(f1.w);
            wxB[kt] = v;
        }
    }

    const int srow = tid >> 6;               // 0..7 staging row
    const int skb  = (tid & 63) << 4;        // staging byte offset
    const int xrow = tid >> 5;               // 0..7 (valid for tid<256)
    const int xkf  = (tid & 31) * 4;

    // prologue: h(0)=0 in both LDS tiles + fp32 state; x(0) for A
    if (tid < MGH*NB){ int row = tid >> 5, c = tid & 31;
        sHfpA[row*33 + c] = 0.f; sHfpB[row*33 + c] = 0.f; }
    { u64x2 z; z[0]=0; z[1]=0;
      *(u64x2*)(sHA + srow*1024 + (skb ^ (srow<<4))) = z;
      *(u64x2*)(sHB + srow*1024 + (skb ^ (srow<<4))) = z; }
    float4 xrA, xrB;
    if (tid < 256){
        xrA = *(const float4*)(src + ((size_t)(b0A + xrow)*TT + 0)*INW + xkf);
        xrB = *(const float4*)(src + ((size_t)(b0B + xrow)*TT + 0)*INW + xkf);
        xwrite(sXA, xrow, xkf, xrA);
    }
    Stg ldA, ldB; ldB.q0 = 0; ldB.q1 = 0;    // h_B(0) = 0, no load needed
    __syncthreads();

    for (int t = 0; t < TT; ++t){
        short* hdst = hbf + (size_t)((t + 1) & 1) * BB * EH;

        // ---- half A: group A step t -----------------------------------------------------------
        enc_compute(sHA, sXA, sR, sZ, sHfpA, whB, wxB, hdst, hencf, b0A, j0,
                    wid, l15, lk, ct, col, t == TT-1);
        wait_vm0(); __syncthreads();
        if (tid == 0) st_coh32(flA + ng*FLS, (unsigned)(t + 1));
        stage_write(sHB, srow, skb, ldB);                   // h_B(t) -> LDS
        if (tid < 256) xwrite(sXB, xrow, xkf, xrB);         // x_B(t) -> LDS
        poll16(flA, (unsigned)(t + 1));
        if (t < TT-1){
            ldA = stage_issue(hdst + (size_t)(b0A + srow)*EH, skb);    // h_A(t+1)
            if (tid < 256)
                xrA = *(const float4*)(src + ((size_t)(b0A + xrow)*TT + (t+1))*INW + xkf);
        }

        // ---- half B: group B step t -----------------------------------------------------------
        enc_compute(sHB, sXB, sR, sZ, sHfpB, whB, wxB, hdst, hencf, b0B, j0,
                    wid, l15, lk, ct, col, t == TT-1);
        wait_vm0(); __syncthreads();
        if (tid == 0) st_coh32(flB + ng*FLS, (unsigned)(t + 1));
        if (t < TT-1){
            stage_write(sHA, srow, skb, ldA);               // h_A(t+1) -> LDS
            if (tid < 256) xwrite(sXA, xrow, xkf, xrA);     // x_A(t+1) -> LDS
        }
        poll16(flB, (unsigned)(t + 1));
        if (t < TT-1){
            ldB = stage_issue(hdst + (size_t)(b0B + srow)*EH, skb);    // h_B(t+1)
            if (tid < 256)
                xrB = *(const float4*)(src + ((size_t)(b0B + xrow)*TT + (t+1))*INW + xkf);
        }
    }
}

// ================= enc2gen linear + reparameterized IC sample =================================
__global__ __launch_bounds__(256) void ic_kernel(
    const float* __restrict__ henc,    // [256][512]
    const float* __restrict__ W,       // [1024][512]
    const float* __restrict__ eps,     // [256][512]
    float*       __restrict__ out_icp, // [256][1024] (output #2)
    float*       __restrict__ gh0f,    // [256][512] f32 generator IC
    short*       __restrict__ gh0b)    // [256][512] bf16 mirror (genH slot0)
{
    __shared__ float hb[EH];
    const int b = blockIdx.x, tid = threadIdx.x;
    for (int k = tid; k < EH; k += 256) hb[k] = henc[(size_t)b*EH + k];
    __syncthreads();

    for (int jj = tid; jj < GH; jj += 256){
        const float4* wm = (const float4*)(W + (size_t)jj * EH);
        const float4* wl = (const float4*)(W + (size_t)(GH + jj) * EH);
        float am = 0.f, al = 0.f;
        #pragma unroll 4
        for (int k4 = 0; k4 < EH/4; ++k4){
            float4 h = ((const float4*)hb)[k4];
            float4 a = wm[k4], c = wl[k4];
            am += h.x*a.x + h.y*a.y + h.z*a.z + h.w*a.w;
            al += h.x*c.x + h.y*c.y + h.z*c.z + h.w*c.w;
        }
        out_icp[(size_t)b*2*GH + jj]      = am;
        out_icp[(size_t)b*2*GH + GH + jj] = al;
        float icv = am + __expf(0.5f * al) * eps[(size_t)b*GH + jj];
        gh0f[(size_t)b*GH + jj] = icv;
        gh0b[(size_t)b*GH + jj] = f2bf(icv);
    }
}

// ================= GENERATOR: 2 phases x 2 multiplexed groups =================================
__global__ __launch_bounds__(512, 1) void gen_kernel(
    const float* __restrict__ Wru,   // [1024][512] rows r then u
    const float* __restrict__ Wc,    // [512][512]
    const float* __restrict__ gh0f,  // [256][512] f32 ic
    short*       __restrict__ hbf,   // [2][256][512] bf16 ping-pong (slot0 = ic mirror)
    short*       __restrict__ rhbf,  // [32][8][512] bf16 r*h exchange (one row-set per group)
    float*       __restrict__ out,   // [256][512][512] (output #1)
    unsigned*    __restrict__ flags)
{
    __shared__ __align__(16) char sHA[MGH*1024];
    __shared__ __align__(16) char sHB[MGH*1024];
    __shared__ float sUA[MGH*33], sUB[MGH*33];
    __shared__ float sHfpA[MGH*33], sHfpB[MGH*33];

    const int bid = blockIdx.x;
    const int pr = bid >> 4, ng = bid & 15;
    const int tid = threadIdx.x;
    const int wid = tid >> 6, lane = tid & 63;
    const int l15 = lane & 15, lk = lane >> 4;
    const int j0 = ng * NB;
    const int b0A = pr * 16, b0B = pr * 16 + 8;
    unsigned* flrA = flags + (size_t)(pr*4 + 0) * (NGB*FLS);
    unsigned* flhA = flags + (size_t)(pr*4 + 1) * (NGB*FLS);
    unsigned* flrB = flags + (size_t)(pr*4 + 2) * (NGB*FLS);
    unsigned* flhB = flags + (size_t)(pr*4 + 3) * (NGB*FLS);
    short* rhgA = rhbf + (size_t)(pr*2 + 0) * MGH * GH;
    short* rhgB = rhbf + (size_t)(pr*2 + 1) * MGH * GH;

    const int gate = wid >> 1, ct = wid & 1;
    const int col = ct*16 + l15;

    // persistent weights: waves 0,1 -> r; 2,3 -> u; 4,5 -> c (shared by A and B)
    bf16x8 wB[16];
    if (wid < 6){
        const float* wr;
        if (gate == 0)      wr = Wru + (size_t)(j0 + col) * GH;
        else if (gate == 1) wr = Wru + (size_t)(GH + j0 + col) * GH;
        else                wr = Wc  + (size_t)(j0 + col) * GH;
        #pragma unroll
        for (int kt = 0; kt < 16; ++kt){
            int ke = kt*32 + lk*8;
            float4 f0 = *(const float4*)(wr + ke);
            float4 f1 = *(const float4*)(wr + ke + 4);
            bf16x8 v;
            v[0]=f2bf(f0.x); v[1]=f2bf(f0.y); v[2]=f2bf(f0.z); v[3]=f2bf(f0.w);
            v[4]=f2bf(f1.x); v[5]=f2bf(f1.y); v[6]=f2bf(f1.z); v[7]=f2bf(f1.w);
            wB[kt] = v;
        }
    }

    const int srow = tid >> 6;
    const int skb  = (tid & 63) << 4;

    // prologue: fp32 state from ic; stage h(0)=ic (slot0) for A now, B deferred
    if (tid < MGH*NB){ int row = tid >> 5, c = tid & 31;
        sHfpA[row*33 + c] = gh0f[(size_t)(b0A + row)*GH + j0 + c];
        sHfpB[row*33 + c] = gh0f[(size_t)(b0B + row)*GH + j0 + c]; }
    Stg ldA = stage_issue(hbf + (size_t)(b0A + srow)*GH, skb);
    Stg ldB = stage_issue(hbf + (size_t)(b0B + srow)*GH, skb);
    stage_write(sHA, srow, skb, ldA);
    __syncthreads();

    for (int t = 0; t < TT; ++t){
        short* slotN = hbf + (size_t)((t + 1) & 1) * BB * GH;

        // ---- P1: ph1_A(t): r,u for A; publish rhA ---------------------------------------------
        gen_ph1(sHA, sUA, sHfpA, wB, rhgA, j0, wid, l15, lk, ct, col);
        wait_vm0(); __syncthreads();
        if (tid == 0) st_coh32(flrA + ng*FLS, (unsigned)(t + 1));
        stage_write(sHB, srow, skb, ldB);                   // h_B(t) -> LDS
        poll16(flrA, (unsigned)(t + 1));
        Stg ldrA = stage_issue(rhgA + (size_t)srow*GH, skb);

        // ---- P2: ph1_B(t) ---------------------------------------------------------------------
        gen_ph1(sHB, sUB, sHfpB, wB, rhgB, j0, wid, l15, lk, ct, col);
        wait_vm0(); __syncthreads();
        if (tid == 0) st_coh32(flrB + ng*FLS, (unsigned)(t + 1));
        stage_write(sHA, srow, skb, ldrA);                  // rhA(t) -> LDS (reuse sHA)
        poll16(flrB, (unsigned)(t + 1));
        Stg ldrB = stage_issue(rhgB + (size_t)srow*GH, skb);

        // ---- P3: ph2_A(t): c + combine; publish h_A(t+1); deferred out stores -----------------
        float hvA[4];
        gen_ph2(sHA, sUA, sHfpA, wB, slotN, b0A, j0, wid, l15, lk, ct, col, hvA);
        wait_vm0(); __syncthreads();
        if (tid == 0) st_coh32(flhA + ng*FLS, (unsigned)(t + 1));
        if (wid == 4 || wid == 5){
            #pragma unroll
            for (int v = 0; v < 4; ++v){ int row = lk*4 + v;
                if (row < MGH)
                    out[((size_t)(b0A + row)*TT + t)*GH + j0 + col] =
                        fminf(fmaxf(hvA[v], -5.0f), 5.0f); }
        }
        stage_write(sHB, srow, skb, ldrB);                  // rhB(t) -> LDS (reuse sHB)
        poll16(flhA, (unsigned)(t + 1));
        if (t < TT-1) ldA = stage_issue(slotN + (size_t)(b0A + srow)*GH, skb);

        // ---- P4: ph2_B(t) ---------------------------------------------------------------------
        float hvB[4];
        gen_ph2(sHB, sUB, sHfpB, wB, slotN, b0B, j0, wid, l15, lk, ct, col, hvB);
        wait_vm0(); __syncthreads();
        if (tid == 0) st_coh32(flhB + ng*FLS, (unsigned)(t + 1));
        if (wid == 4 || wid == 5){
            #pragma unroll
            for (int v = 0; v < 4; ++v){ int row = lk*4 + v;
                if (row < MGH)
                    out[((size_t)(b0B + row)*TT + t)*GH + j0 + col] =
                        fminf(fmaxf(hvB[v], -5.0f), 5.0f); }
        }
        if (t < TT-1) stage_write(sHA, srow, skb, ldA);     // h_A(t+1) -> LDS
        poll16(flhB, (unsigned)(t + 1));
        if (t < TT-1) ldB = stage_issue(slotN + (size_t)(b0B + srow)*GH, skb);
    }
}

extern "C" void kernel_launch(void* const* d_in, const int* in_sizes, int n_in,
                              void* d_out, int out_size, void* d_ws, size_t ws_size,
                              hipStream_t stream) {
    (void)in_sizes; (void)n_in; (void)out_size; (void)ws_size;

    const float* src    = (const float*)d_in[0];
    const float* eps    = (const float*)d_in[1];
    const float* enc_Wi = (const float*)d_in[2];
    const float* enc_Wh = (const float*)d_in[3];
    const float* e2g    = (const float*)d_in[4];
    const float* gWru   = (const float*)d_in[5];
    const float* gWc    = (const float*)d_in[6];
    float* out = (float*)d_out;

    // workspace layout (~2.38 MB):
    char* ws = (char*)d_ws;
    unsigned* encFl = (unsigned*)ws;                         // 32 KB: 16 pairs x 2 groups x 1KB
    unsigned* genFl = (unsigned*)(ws + 32768);               // 64 KB: 16 pairs x 4 arrays x 1KB
    float* hencf = (float*)(ws + 131072);                    // 512 KB [256][512] f32
    float* gh0f  = (float*)(ws + 131072 + 512*1024);         // 512 KB
    short* encH  = (short*)(ws + 131072 + 1024*1024);        // 512 KB [2][256][512] bf16
    short* genH  = (short*)(ws + 131072 + 1536*1024);        // 512 KB
    short* rhbf  = (short*)(ws + 131072 + 2048*1024);        // 256 KB [32][8][512] bf16

    hipMemsetAsync(ws, 0, 98304, stream);                    // all flags = 0
    hipMemsetAsync(encH, 0, (size_t)BB*EH*2, stream);        // enc h(0) = 0 (slot 0)

    enc_kernel<<<dim3(256), dim3(512), 0, stream>>>(src, enc_Wi, enc_Wh, encH, hencf, encFl);
    ic_kernel <<<dim3(256), dim3(256), 0, stream>>>(hencf, e2g, eps,
                                                    out + (size_t)BB*TT*GH, gh0f, genH);
    gen_kernel<<<dim3(256), dim3(512), 0, stream>>>(gWru, gWc, gh0f, genH, rhbf, out,
                                                    genFl);
}

// Round 7
// 6179.880 us; speedup vs baseline: 1.1744x; 1.1744x over previous
//
#include <hip/hip_runtime.h>
#include <hip/hip_bf16.h>
#include <math.h>

#define BB 256
#define TT 512
#define INW 128
#define EH 512
#define GH 512

#define NGB 16           // column-slice blocks per group
#define MGH 8            // batch rows per pipelined group
#define NB 32            // output cols per block (2 x 16-col tiles)
#define HXS (BB*256)     // u64 words per tagged h slot  [256 rows][256 col-pairs]

typedef __attribute__((ext_vector_type(8))) short bf16x8;
typedef __attribute__((ext_vector_type(4))) float f32x4;
typedef __attribute__((ext_vector_type(4))) unsigned int u32x4;
typedef unsigned long long ull;

__device__ __forceinline__ float sigm(float x){ return 1.0f/(1.0f+__expf(-x)); }
__device__ __forceinline__ short f2bf(float x){
    __hip_bfloat16 h = __float2bfloat16(x);
    return *reinterpret_cast<short*>(&h);
}

// agent-scope relaxed (IC-coherent) — the proven r3/r4 data path
__device__ __forceinline__ ull ld_coh64(const ull* p){
    return __hip_atomic_load(p, __ATOMIC_RELAXED, __HIP_MEMORY_SCOPE_AGENT);
}
__device__ __forceinline__ void st_coh64(ull* p, ull v){
    __hip_atomic_store(p, v, __ATOMIC_RELAXED, __HIP_MEMORY_SCOPE_AGENT);
}

// validate-and-stage: 4 tagged u64 per thread -> one swizzled 16B LDS chunk.
// Spins reloading only not-yet-valid words; producers never wait on anything.
__device__ __forceinline__ void vstage4(const ull* gp, unsigned e, char* sbuf,
                                        int row, int kb0){
    unsigned d[4]; unsigned okm = 0; long spins = 0;
    for (;;){
        ull w[4];
        #pragma unroll
        for (int k = 0; k < 4; ++k) if (!(okm & (1u<<k))) w[k] = ld_coh64(gp + k);
        #pragma unroll
        for (int k = 0; k < 4; ++k)
            if (!(okm & (1u<<k)) && (unsigned)(w[k] >> 32) == e){
                d[k] = (unsigned)w[k]; okm |= (1u<<k);
            }
        if (okm == 15u) break;
        if (++spins > (1L << 20)) break;   // escape hatch, never hit legitimately
    }
    u32x4 a; a[0]=d[0]; a[1]=d[1]; a[2]=d[2]; a[3]=d[3];
    *(u32x4*)(sbuf + row*1024 + (kb0 ^ ((row & 7) << 4))) = a;
}

// x-tile: pack 4 fp32 -> 4 bf16 at swizzled LDS offset
__device__ __forceinline__ void xpack(char* sX, int row, int kf, float4 f){
    short4 v; v.x=f2bf(f.x); v.y=f2bf(f.y); v.z=f2bf(f.z); v.w=f2bf(f.w);
    *(short4*)(sX + row*256 + ((kf*2) ^ ((row & 7) << 4))) = v;
}

// ---------------- encoder one GRU step (r6-verified compute, tagged publish) ------------------
__device__ __forceinline__ void enc_step(
    const char* sH, const char* sX, float* sR, float* sZ, float* sHfp,
    const bf16x8* whB, const bf16x8* wxB,
    ull* pubN, unsigned e, float* hencf,
    int b0, int j0, int wid, int l15, int lk, int ct, int col, bool last)
{
    f32x4 acc0={0.f,0.f,0.f,0.f}, acc1={0.f,0.f,0.f,0.f}, accx={0.f,0.f,0.f,0.f};
    if (wid < 6){
        const int r8 = l15 & 7, asw = r8 << 4;
        const char* hb = sH + r8*1024;
        const char* xb = sX + r8*256;
        #pragma unroll
        for (int kt = 0; kt < 8; ++kt){ int kb = kt*64 + lk*16;
            acc0 = __builtin_amdgcn_mfma_f32_16x16x32_bf16(*(const bf16x8*)(hb+(kb^asw)), whB[kt], acc0, 0,0,0); }
        #pragma unroll
        for (int kt = 8; kt < 16; ++kt){ int kb = kt*64 + lk*16;
            acc1 = __builtin_amdgcn_mfma_f32_16x16x32_bf16(*(const bf16x8*)(hb+(kb^asw)), whB[kt], acc1, 0,0,0); }
        #pragma unroll
        for (int kt = 0; kt < 4; ++kt){ int kb = kt*64 + lk*16;
            accx = __builtin_amdgcn_mfma_f32_16x16x32_bf16(*(const bf16x8*)(xb+(kb^asw)), wxB[kt], accx, 0,0,0); }
    }
    f32x4 acch = acc0 + acc1;
    if (wid < 2){
        #pragma unroll
        for (int v = 0; v < 4; ++v){ int row = lk*4 + v;
            if (row < MGH) sR[row*33 + col] = sigm(accx[v] + acch[v]); }
    } else if (wid < 4){
        #pragma unroll
        for (int v = 0; v < 4; ++v){ int row = lk*4 + v;
            if (row < MGH) sZ[row*33 + col] = sigm(accx[v] + acch[v]); }
    }
    __syncthreads();
    if (wid == 4 || wid == 5){
        #pragma unroll
        for (int v = 0; v < 4; ++v){ int row = lk*4 + v;
            if (row < MGH){
                float r  = sR[row*33 + col];
                float z  = sZ[row*33 + col];
                float n  = tanhf(accx[v] + r * acch[v]);
                float hp = sHfp[row*33 + col];
                float hn = (1.f - z)*n + z*hp;
                sHfp[row*33 + col] = hn;
                if (!last){
                    unsigned mine = (unsigned short)f2bf(hn);
                    unsigned oth  = __shfl_xor(mine, 1);
                    if (!(l15 & 1))
                        st_coh64(pubN + (size_t)(b0+row)*256 + ((j0 + ct*16 + l15) >> 1),
                                 ((ull)e << 32) | ((ull)oth << 16) | mine);
                } else {
                    hencf[(size_t)(b0+row)*EH + j0 + col] = hn;
                }
            }
        }
    }
}

// ---------------- generator phases (r6-verified compute, tagged publish) ----------------------
__device__ __forceinline__ void gen_ph1(
    const char* sH, float* sU, const float* sHfp, const bf16x8* wB,
    ull* rhg, unsigned e, int j0, int wid, int l15, int lk, int ct, int col)
{
    if (wid < 4){
        const int r8 = l15 & 7, asw = r8 << 4;
        const char* hb = sH + r8*1024;
        f32x4 a0={0.f,0.f,0.f,0.f}, a1={0.f,0.f,0.f,0.f};
        #pragma unroll
        for (int kt = 0; kt < 8; ++kt){ int kb = kt*64 + lk*16;
            a0 = __builtin_amdgcn_mfma_f32_16x16x32_bf16(*(const bf16x8*)(hb+(kb^asw)), wB[kt], a0, 0,0,0); }
        #pragma unroll
        for (int kt = 8; kt < 16; ++kt){ int kb = kt*64 + lk*16;
            a1 = __builtin_amdgcn_mfma_f32_16x16x32_bf16(*(const bf16x8*)(hb+(kb^asw)), wB[kt], a1, 0,0,0); }
        f32x4 acc = a0 + a1;
        if (wid < 2){
            #pragma unroll
            for (int v = 0; v < 4; ++v){ int row = lk*4 + v;
                if (row < MGH){
                    float hp = sHfp[row*33 + col];
                    float rv = sigm(acc[v]);
                    unsigned mine = (unsigned short)f2bf(rv * hp);
                    unsigned oth  = __shfl_xor(mine, 1);
                    if (!(l15 & 1))
                        st_coh64(rhg + (size_t)row*256 + ((j0 + ct*16 + l15) >> 1),
                                 ((ull)e << 32) | ((ull)oth << 16) | mine);
                }}
        } else {
            #pragma unroll
            for (int v = 0; v < 4; ++v){ int row = lk*4 + v;
                if (row < MGH) sU[row*33 + col] = sigm(acc[v] + 1.0f); }
        }
    }
}

__device__ __forceinline__ void gen_ph2(
    const char* sRH, const float* sU, float* sHfp, const bf16x8* wB,
    ull* pubN, unsigned e, float* out, int t, int b0, int j0,
    int wid, int l15, int lk, int ct, int col)
{
    if (wid == 4 || wid == 5){
        const int r8 = l15 & 7, asw = r8 << 4;
        const char* hb = sRH + r8*1024;
        f32x4 a0={0.f,0.f,0.f,0.f}, a1={0.f,0.f,0.f,0.f};
        #pragma unroll
        for (int kt = 0; kt < 8; ++kt){ int kb = kt*64 + lk*16;
            a0 = __builtin_amdgcn_mfma_f32_16x16x32_bf16(*(const bf16x8*)(hb+(kb^asw)), wB[kt], a0, 0,0,0); }
        #pragma unroll
        for (int kt = 8; kt < 16; ++kt){ int kb = kt*64 + lk*16;
            a1 = __builtin_amdgcn_mfma_f32_16x16x32_bf16(*(const bf16x8*)(hb+(kb^asw)), wB[kt], a1, 0,0,0); }
        f32x4 acc = a0 + a1;
        #pragma unroll
        for (int v = 0; v < 4; ++v){ int row = lk*4 + v;
            if (row < MGH){
                float cv = tanhf(acc[v]);
                float u  = sU[row*33 + col];
                float hp = sHfp[row*33 + col];
                float hn = u*hp + (1.f - u)*cv;
                sHfp[row*33 + col] = hn;
                unsigned mine = (unsigned short)f2bf(hn);
                unsigned oth  = __shfl_xor(mine, 1);
                if (!(l15 & 1))
                    st_coh64(pubN + (size_t)(b0+row)*256 + ((j0 + ct*16 + l15) >> 1),
                             ((ull)e << 32) | ((ull)oth << 16) | mine);
                out[((size_t)(b0+row)*TT + t)*GH + j0 + col] = fminf(fmaxf(hn, -5.f), 5.f);
            }
        }
    }
}

// ================= ENCODER: tagged dataflow, 2-group pipeline =================================
__global__ __launch_bounds__(512, 1) void enc_kernel(
    const float* __restrict__ src,   // [256][512][128]
    const float* __restrict__ Wi,    // [1536][128]
    const float* __restrict__ Wh,    // [1536][512]
    ull*         __restrict__ hx,    // [2][256][256] tagged
    float*       __restrict__ hencf) // [256][512] f32 (aliased on genHx slot1)
{
    __shared__ __align__(16) char sHA[MGH*1024], sHB[MGH*1024];
    __shared__ __align__(16) char sXA[MGH*256],  sXB[MGH*256];
    __shared__ float sR[MGH*33], sZ[MGH*33], sHfpA[MGH*33], sHfpB[MGH*33];

    const int bid = blockIdx.x, pr = bid >> 4, ng = bid & 15;
    const int tid = threadIdx.x, wid = tid >> 6, lane = tid & 63;
    const int l15 = lane & 15, lk = lane >> 4;
    const int j0 = ng * NB, b0A = pr*16, b0B = pr*16 + 8;
    const int gate = wid >> 1, ct = wid & 1, col = ct*16 + l15;

    bf16x8 whB[16], wxB[4];
    if (wid < 6){
        const float* wrh = Wh + (size_t)(gate*EH + j0 + col) * EH;
        const float* wrx = Wi + (size_t)(gate*EH + j0 + col) * INW;
        #pragma unroll
        for (int kt = 0; kt < 16; ++kt){
            int ke = kt*32 + lk*8;
            float4 f0 = *(const float4*)(wrh + ke);
            float4 f1 = *(const float4*)(wrh + ke + 4);
            bf16x8 v;
            v[0]=f2bf(f0.x); v[1]=f2bf(f0.y); v[2]=f2bf(f0.z); v[3]=f2bf(f0.w);
            v[4]=f2bf(f1.x); v[5]=f2bf(f1.y); v[6]=f2bf(f1.z); v[7]=f2bf(f1.w);
            whB[kt] = v;
        }
        #pragma unroll
        for (int kt = 0; kt < 4; ++kt){
            int ke = kt*32 + lk*8;
            float4 f0 = *(const float4*)(wrx + ke);
            float4 f1 = *(const float4*)(wrx + ke + 4);
            bf16x8 v;
            v[0]=f2bf(f0.x); v[1]=f2bf(f0.y); v[2]=f2bf(f0.z); v[3]=f2bf(f0.w);
            v[4]=f2bf(f1.x); v[5]=f2bf(f1.y); v[6]=f2bf(f1.z); v[7]=f2bf(f1.w);
            wxB[kt] = v;
        }
    }

    const int vrow = tid >> 6, vp0 = (tid & 63)*4, vkb = (tid & 63)*16;
    const int xrow = tid >> 5, xkf = (tid & 31)*4;       // valid for tid<256

    // prologue: h(0)=0 directly in LDS (never touches global); x(0) staged
    if (tid < 256){ int row = tid >> 5, c = tid & 31;
        sHfpA[row*33 + c] = 0.f; sHfpB[row*33 + c] = 0.f; }
    { u32x4 z = {0,0,0,0};
      *(u32x4*)(sHA + vrow*1024 + (vkb ^ ((vrow & 7) << 4))) = z;
      *(u32x4*)(sHB + vrow*1024 + (vkb ^ ((vrow & 7) << 4))) = z; }
    if (tid < 256){
        float4 fA = *(const float4*)(src + ((size_t)(b0A + xrow)*TT + 0)*INW + xkf);
        float4 fB = *(const float4*)(src + ((size_t)(b0B + xrow)*TT + 0)*INW + xkf);
        xpack(sXA, xrow, xkf, fA);
        xpack(sXB, xrow, xkf, fB);
    }
    __syncthreads();

    for (int t = 0; t < TT; ++t){
        ull* pubN = hx + (size_t)((t+1) & 1) * HXS;
        const bool last = (t == TT-1);
        float4 xfA, xfB;
        if (!last && tid < 256){        // issue x(t+1) loads early; pack later
            xfA = *(const float4*)(src + ((size_t)(b0A + xrow)*TT + (t+1))*INW + xkf);
            xfB = *(const float4*)(src + ((size_t)(b0B + xrow)*TT + (t+1))*INW + xkf);
        }
        // p1: group A step t; publish h_A(t+1)
        enc_step(sHA, sXA, sR, sZ, sHfpA, whB, wxB, pubN, (unsigned)(t+1), hencf,
                 b0A, j0, wid, l15, lk, ct, col, last);
        __syncthreads();
        // p2: validate h_B(t) (published 2 stages ago); pack x_A(t+1)
        if (t >= 1)
            vstage4(hx + (size_t)(t & 1)*HXS + (size_t)(b0B + vrow)*256 + vp0,
                    (unsigned)t, sHB, vrow, vkb);
        if (!last && tid < 256) xpack(sXA, xrow, xkf, xfA);
        __syncthreads();
        // p3: group B step t; publish h_B(t+1)
        enc_step(sHB, sXB, sR, sZ, sHfpB, whB, wxB, pubN, (unsigned)(t+1), hencf,
                 b0B, j0, wid, l15, lk, ct, col, last);
        __syncthreads();
        // p4: validate h_A(t+1) (published 2 stages ago); pack x_B(t+1)
        if (!last){
            vstage4(pubN + (size_t)(b0A + vrow)*256 + vp0, (unsigned)(t+1), sHA, vrow, vkb);
            if (tid < 256) xpack(sXB, xrow, xkf, xfB);
            __syncthreads();
        }
    }
}

// ================= enc2gen linear + reparameterized IC sample =================================
__global__ __launch_bounds__(256) void ic_kernel(
    const float* __restrict__ henc,    // [256][512]
    const float* __restrict__ W,       // [1024][512]
    const float* __restrict__ eps,     // [256][512]
    float*       __restrict__ out_icp, // [256][1024] (output #2)
    float*       __restrict__ gh0f,    // [256][512] f32 IC (aliased on encHx slot0)
    ull*         __restrict__ gh0x)    // genHx slot0: tagged epoch-0 IC mirror
{
    __shared__ float hb[EH];
    __shared__ float sIC[GH];
    const int b = blockIdx.x, tid = threadIdx.x;
    for (int k = tid; k < EH; k += 256) hb[k] = henc[(size_t)b*EH + k];
    __syncthreads();

    for (int jj = tid; jj < GH; jj += 256){
        const float4* wm = (const float4*)(W + (size_t)jj * EH);
        const float4* wl = (const float4*)(W + (size_t)(GH + jj) * EH);
        float am = 0.f, al = 0.f;
        #pragma unroll 4
        for (int k4 = 0; k4 < EH/4; ++k4){
            float4 h = ((const float4*)hb)[k4];
            float4 a = wm[k4], c = wl[k4];
            am += h.x*a.x + h.y*a.y + h.z*a.z + h.w*a.w;
            al += h.x*c.x + h.y*c.y + h.z*c.z + h.w*c.w;
        }
        out_icp[(size_t)b*2*GH + jj]      = am;
        out_icp[(size_t)b*2*GH + GH + jj] = al;
        float icv = am + __expf(0.5f * al) * eps[(size_t)b*GH + jj];
        gh0f[(size_t)b*GH + jj] = icv;
        sIC[jj] = icv;
    }
    __syncthreads();
    {   // pack tagged epoch-0 pairs (256 pairs per batch row)
        int p = tid;
        unsigned mine = (unsigned short)f2bf(sIC[2*p]);
        unsigned oth  = (unsigned short)f2bf(sIC[2*p + 1]);
        st_coh64(gh0x + (size_t)b*256 + p, ((ull)oth << 16) | mine);   // tag 0
    }
}

// ================= GENERATOR: tagged dataflow, 2-group 8-stage pipeline =======================
__global__ __launch_bounds__(512, 1) void gen_kernel(
    const float* __restrict__ Wru,   // [1024][512]
    const float* __restrict__ Wc,    // [512][512]
    const float* __restrict__ gh0f,  // [256][512] f32 ic
    ull*         __restrict__ hx,    // [2][256][256] tagged (slot0 = ic tag 0)
    ull*         __restrict__ rh,    // [32][8][256] tagged r*h exchange
    float*       __restrict__ out)   // [256][512][512] (output #1)
{
    __shared__ __align__(16) char sHA[MGH*1024], sHB[MGH*1024];
    __shared__ __align__(16) char sRA[MGH*1024], sRB[MGH*1024];
    __shared__ float sUA[MGH*33], sUB[MGH*33], sHfpA[MGH*33], sHfpB[MGH*33];

    const int bid = blockIdx.x, pr = bid >> 4, ng = bid & 15;
    const int tid = threadIdx.x, wid = tid >> 6, lane = tid & 63;
    const int l15 = lane & 15, lk = lane >> 4;
    const int j0 = ng * NB, b0A = pr*16, b0B = pr*16 + 8;
    const int gate = wid >> 1, ct = wid & 1, col = ct*16 + l15;

    bf16x8 wB[16];
    if (wid < 6){
        const float* wr;
        if (gate == 0)      wr = Wru + (size_t)(j0 + col) * GH;
        else if (gate == 1) wr = Wru + (size_t)(GH + j0 + col) * GH;
        else                wr = Wc  + (size_t)(j0 + col) * GH;
        #pragma unroll
        for (int kt = 0; kt < 16; ++kt){
            int ke = kt*32 + lk*8;
            float4 f0 = *(const float4*)(wr + ke);
            float4 f1 = *(const float4*)(wr + ke + 4);
            bf16x8 v;
            v[0]=f2bf(f0.x); v[1]=f2bf(f0.y); v[2]=f2bf(f0.z); v[3]=f2bf(f0.w);
            v[4]=f2bf(f1.x); v[5]=f2bf(f1.y); v[6]=f2bf(f1.z); v[7]=f2bf(f1.w);
            wB[kt] = v;
        }
    }

    const int vrow = tid >> 6, vp0 = (tid & 63)*4, vkb = (tid & 63)*16;
    ull* rhgA = rh + (size_t)(pr*2 + 0) * (MGH*256);
    ull* rhgB = rh + (size_t)(pr*2 + 1) * (MGH*256);

    // prologue: fp32 state + tagged IC (epoch 0) into LDS
    if (tid < 256){ int row = tid >> 5, c = tid & 31;
        sHfpA[row*33 + c] = gh0f[(size_t)(b0A + row)*GH + j0 + c];
        sHfpB[row*33 + c] = gh0f[(size_t)(b0B + row)*GH + j0 + c]; }
    vstage4(hx + (size_t)(b0A + vrow)*256 + vp0, 0u, sHA, vrow, vkb);
    vstage4(hx + (size_t)(b0B + vrow)*256 + vp0, 0u, sHB, vrow, vkb);
    __syncthreads();

    for (int t = 0; t < TT; ++t){
        ull* pubN = hx + (size_t)((t+1) & 1) * HXS;
        const unsigned e = (unsigned)(t + 1);

        // g1: ph1_A -> publish rhA
        gen_ph1(sHA, sUA, sHfpA, wB, rhgA, e, j0, wid, l15, lk, ct, col);
        __syncthreads();
        // g2: validate h_B(t) (published end of prev iter)
        if (t >= 1)
            vstage4(hx + (size_t)(t & 1)*HXS + (size_t)(b0B + vrow)*256 + vp0,
                    (unsigned)t, sHB, vrow, vkb);
        __syncthreads();
        // g3: ph1_B -> publish rhB
        gen_ph1(sHB, sUB, sHfpB, wB, rhgB, e, j0, wid, l15, lk, ct, col);
        __syncthreads();
        // g4: validate rhA (2 stages since publish)
        vstage4(rhgA + (size_t)vrow*256 + vp0, e, sRA, vrow, vkb);
        __syncthreads();
        // g5: ph2_A -> publish h_A(t+1), out
        gen_ph2(sRA, sUA, sHfpA, wB, pubN, e, out, t, b0A, j0, wid, l15, lk, ct, col);
        __syncthreads();
        // g6: validate rhB
        vstage4(rhgB + (size_t)vrow*256 + vp0, e, sRB, vrow, vkb);
        __syncthreads();
        // g7: ph2_B -> publish h_B(t+1), out
        gen_ph2(sRB, sUB, sHfpB, wB, pubN, e, out, t, b0B, j0, wid, l15, lk, ct, col);
        __syncthreads();
        // g8: validate h_A(t+1)
        if (t < TT-1){
            vstage4(pubN + (size_t)(b0A + vrow)*256 + vp0, e, sHA, vrow, vkb);
            __syncthreads();
        }
    }
}

extern "C" void kernel_launch(void* const* d_in, const int* in_sizes, int n_in,
                              void* d_out, int out_size, void* d_ws, size_t ws_size,
                              hipStream_t stream) {
    (void)in_sizes; (void)n_in; (void)out_size; (void)ws_size;

    const float* src    = (const float*)d_in[0];
    const float* eps    = (const float*)d_in[1];
    const float* enc_Wi = (const float*)d_in[2];
    const float* enc_Wh = (const float*)d_in[3];
    const float* e2g    = (const float*)d_in[4];
    const float* gWru   = (const float*)d_in[5];
    const float* gWc    = (const float*)d_in[6];
    float* out = (float*)d_out;

    // workspace (2.5 MB), with safe lifetime-based aliasing:
    //  [0,1MB)      encHx tagged [2][256][256]  (slot0 region reused as gh0f after enc)
    //  [1MB,2MB)    genHx tagged [2][256][256]  (slot1 region holds hencf until gen starts)
    //  [2MB,2.5MB)  rh tagged [32][8][256]
    char* ws = (char*)d_ws;
    ull*   encHx = (ull*)(ws);
    ull*   genHx = (ull*)(ws + (1u<<20));
    ull*   rhbuf = (ull*)(ws + (2u<<20));
    float* gh0f  = (float*)(ws);                          // aliases encHx slot0 (enc done)
    float* hencf = (float*)(ws + (1u<<20) + (512u<<10));  // aliases genHx slot1 (ic done before gen)

    enc_kernel<<<dim3(256), dim3(512), 0, stream>>>(src, enc_Wi, enc_Wh, encHx, hencf);
    ic_kernel <<<dim3(256), dim3(256), 0, stream>>>(hencf, e2g, eps,
                                                    out + (size_t)BB*TT*GH, gh0f, genHx);
    gen_kernel<<<dim3(256), dim3(512), 0, stream>>>(gWru, gWc, gh0f, genHx, rhbuf, out);
}